// Round 1
// baseline (217.446 us; speedup 1.0000x reference)
//
#include <hip/hip_runtime.h>
#include <math.h>

#define BSZ    4
#define NTOK   6400      // 40*160
#define DMODEL 256
#define NHEAD  8
#define HDIM   32
#define NPTS   9
#define HSP    40
#define WSP    160
#define KDIM   256
#define MTOT   (BSZ*NTOK)   // 25600

typedef short  short8  __attribute__((ext_vector_type(8)));
typedef float  floatx4 __attribute__((ext_vector_type(4)));
typedef float  f32x2   __attribute__((ext_vector_type(2)));

__device__ __forceinline__ ushort f2bf(float f) {
    uint u = __float_as_uint(f);
    u = (u + 0x7FFFu + ((u >> 16) & 1u)) >> 16;   // RNE
    return (ushort)u;
}

// unpack 8 packed bf16 (uint4) -> 4 x f32x2 (pairs, channel order preserved)
__device__ __forceinline__ void unpack8v(uint4 u, f32x2* f) {
    f[0].x = __uint_as_float(u.x << 16); f[0].y = __uint_as_float(u.x & 0xFFFF0000u);
    f[1].x = __uint_as_float(u.y << 16); f[1].y = __uint_as_float(u.y & 0xFFFF0000u);
    f[2].x = __uint_as_float(u.z << 16); f[2].y = __uint_as_float(u.z & 0xFFFF0000u);
    f[3].x = __uint_as_float(u.w << 16); f[3].y = __uint_as_float(u.w & 0xFFFF0000u);
}

// dot of 8 bf16 (packed in uint4) with q2[4] (f32x2 pairs) -> scalar
__device__ __forceinline__ float dot8(uint4 u, const f32x2* q2) {
    f32x2 a; a.x = 0.f; a.y = 0.f;
    f32x2 t;
    t.x = __uint_as_float(u.x << 16); t.y = __uint_as_float(u.x & 0xFFFF0000u);
    a += t * q2[0];
    t.x = __uint_as_float(u.y << 16); t.y = __uint_as_float(u.y & 0xFFFF0000u);
    a += t * q2[1];
    t.x = __uint_as_float(u.z << 16); t.y = __uint_as_float(u.z & 0xFFFF0000u);
    a += t * q2[2];
    t.x = __uint_as_float(u.w << 16); t.y = __uint_as_float(u.w & 0xFFFF0000u);
    a += t * q2[3];
    return a.x + a.y;
}

#define AS1C(p) ((const __attribute__((address_space(1))) void*)(p))
#define AS3(p)  ((__attribute__((address_space(3))) void*)(p))

// ---------------------------------------------------------------------------
// All fp32->bf16 casts in one launch. Block = 1024 elems.
// Builds the fused weight buffer wf (1024 rows x 256 k, bf16):
//   rows [0,256)    = Wq
//   rows [256,400)  = Woff
//   rows [400,512)  = zeros (pad)
//   rows [512,1024) = Wkv
// ranges: x 6400 | Wq 64 | Woff 36 | zero 28 | Wkv 128 | Wout 64 => 6720 blocks
// ---------------------------------------------------------------------------
__global__ __launch_bounds__(256) void cast_all(
    const float* __restrict__ x,   const float* __restrict__ Wq,
    const float* __restrict__ Woff,const float* __restrict__ Wkv,
    const float* __restrict__ Wout,
    ushort* __restrict__ xb, ushort* __restrict__ wf, ushort* __restrict__ woutb)
{
    const int bid = blockIdx.x;
    if (bid >= 6500 && bid < 6528) {           // zero-fill pad rows 400..511
        const int i = (bid - 6500) * 1024 + threadIdx.x * 4;
        ushort4 z; z.x = 0; z.y = 0; z.z = 0; z.w = 0;
        *(ushort4*)(wf + 400 * 256 + i) = z;
        return;
    }
    const float* src; ushort* dst; int base;
    if      (bid < 6400) { src = x;    dst = xb;              base = bid; }
    else if (bid < 6464) { src = Wq;   dst = wf;              base = bid - 6400; }
    else if (bid < 6500) { src = Woff; dst = wf + 256 * 256;  base = bid - 6464; }
    else if (bid < 6656) { src = Wkv;  dst = wf + 512 * 256;  base = bid - 6528; }
    else                 { src = Wout; dst = woutb;           base = bid - 6656; }
    const int i = base * 1024 + threadIdx.x * 4;
    float4 v = *(const float4*)(src + i);
    ushort4 o;
    o.x = f2bf(v.x); o.y = f2bf(v.y); o.z = f2bf(v.z); o.w = f2bf(v.w);
    *(ushort4*)(dst + i) = o;
}

// ---------------------------------------------------------------------------
// Fused bf16 MFMA GEMM: Y[1024 cols] = X @ [Wq; Woff; pad; Wkv]^T
// m97-style global_load_lds(16B) staging, 128x128 tile, grid (8, 200).
// Epilogue dispatches per column region:
//   [0,256)    -> qb bf16
//   [256,400)  -> off fp32 tanh*4 (ld 144)
//   [400,512)  -> discard
//   [512,1024) -> scatter bf16 -> kfb / vfb (B*H, N, 32)
// ---------------------------------------------------------------------------
__global__ __launch_bounds__(256) void gemm_fused(
    const ushort* __restrict__ Xb,
    const ushort* __restrict__ Wf,
    const float* __restrict__ bq, const float* __restrict__ boff,
    const float* __restrict__ bkv,
    ushort* __restrict__ qb, float* __restrict__ off,
    ushort* __restrict__ kfb, ushort* __restrict__ vfb)
{
    __shared__ ushort As[128 * 32];
    __shared__ ushort Bs[128 * 32];

    const int tid = threadIdx.x;
    const int block_m = blockIdx.y * 128;
    const int block_n = blockIdx.x * 128;
    const int wave = tid >> 6, lane = tid & 63;
    const int wm = (wave >> 1) * 64, wn = (wave & 1) * 64;
    const int l15 = lane & 15, quad = lane >> 4;

    const int srow = wave * 32 + (lane >> 2);
    const int scol = (lane & 3) * 8;

    const ushort* gA0 = Xb + (size_t)(block_m + srow) * KDIM + scol;
    const ushort* gA1 = gA0 + 16 * KDIM;
    const ushort* gB0 = Wf + (size_t)(block_n + srow) * KDIM + scol;
    const ushort* gB1 = gB0 + 16 * KDIM;

    ushort* lA0 = &As[(wave * 32) * 32];
    ushort* lA1 = &As[(wave * 32 + 16) * 32];
    ushort* lB0 = &Bs[(wave * 32) * 32];
    ushort* lB1 = &Bs[(wave * 32 + 16) * 32];

    floatx4 acc[4][4];
    #pragma unroll
    for (int i = 0; i < 4; ++i)
        #pragma unroll
        for (int j = 0; j < 4; ++j) {
            acc[i][j][0] = 0.f; acc[i][j][1] = 0.f;
            acc[i][j][2] = 0.f; acc[i][j][3] = 0.f;
        }

    for (int k0 = 0; k0 < KDIM; k0 += 32) {
        __builtin_amdgcn_global_load_lds(AS1C(gA0 + k0), AS3(lA0), 16, 0, 0);
        __builtin_amdgcn_global_load_lds(AS1C(gA1 + k0), AS3(lA1), 16, 0, 0);
        __builtin_amdgcn_global_load_lds(AS1C(gB0 + k0), AS3(lB0), 16, 0, 0);
        __builtin_amdgcn_global_load_lds(AS1C(gB1 + k0), AS3(lB1), 16, 0, 0);
        __syncthreads();

        short8 af[4], bfr[4];
        #pragma unroll
        for (int f = 0; f < 4; ++f) {
            af[f]  = *(const short8*)&As[(wm + f * 16 + l15) * 32 + quad * 8];
            bfr[f] = *(const short8*)&Bs[(wn + f * 16 + l15) * 32 + quad * 8];
        }
        #pragma unroll
        for (int fm = 0; fm < 4; ++fm)
            #pragma unroll
            for (int fn = 0; fn < 4; ++fn)
                acc[fm][fn] = __builtin_amdgcn_mfma_f32_16x16x32_bf16(
                    af[fm], bfr[fn], acc[fm][fn], 0, 0, 0);
        __syncthreads();
    }

    // epilogue: C/D layout col=lane&15, row=quad*4+reg
    #pragma unroll
    for (int fn = 0; fn < 4; ++fn) {
        const int col = block_n + wn + fn * 16 + l15;
        float bcol;
        if      (col < 256) bcol = bq[col];
        else if (col < 400) bcol = boff[col - 256];
        else if (col < 512) bcol = 0.f;
        else                bcol = bkv[col - 512];
        #pragma unroll
        for (int fm = 0; fm < 4; ++fm) {
            #pragma unroll
            for (int r = 0; r < 4; ++r) {
                const int row = block_m + wm + fm * 16 + quad * 4 + r;
                const float val = acc[fm][fn][r] + bcol;
                if (col < 256) {
                    qb[(size_t)row * DMODEL + col] = f2bf(val);
                } else if (col < 400) {
                    off[(size_t)row * 144 + (col - 256)] = tanhf(val) * 4.0f;
                } else if (col >= 512) {
                    const int c2 = col - 512;
                    const int bb = row / NTOK, nn = row % NTOK;
                    const int hh = (c2 & 255) >> 5, cc = c2 & 31;
                    const size_t o = (((size_t)(bb * NHEAD + hh)) * NTOK + nn) * HDIM + cc;
                    if (c2 < 256) kfb[o] = f2bf(val);
                    else          vfb[o] = f2bf(val);
                }
            }
        }
    }
}

// ---------------------------------------------------------------------------
// Final projection GEMM: fp32 out (M,256)
// ---------------------------------------------------------------------------
__global__ __launch_bounds__(256) void gemm_out(
    const ushort* __restrict__ Xb,
    const ushort* __restrict__ Wb,
    const float* __restrict__ bias,
    float* __restrict__ Y)
{
    __shared__ ushort As[128 * 32];
    __shared__ ushort Bs[128 * 32];

    const int tid = threadIdx.x;
    const int block_m = blockIdx.y * 128;
    const int block_n = blockIdx.x * 128;
    const int wave = tid >> 6, lane = tid & 63;
    const int wm = (wave >> 1) * 64, wn = (wave & 1) * 64;
    const int l15 = lane & 15, quad = lane >> 4;

    const int srow = wave * 32 + (lane >> 2);
    const int scol = (lane & 3) * 8;

    const ushort* gA0 = Xb + (size_t)(block_m + srow) * KDIM + scol;
    const ushort* gA1 = gA0 + 16 * KDIM;
    const ushort* gB0 = Wb + (size_t)(block_n + srow) * KDIM + scol;
    const ushort* gB1 = gB0 + 16 * KDIM;

    ushort* lA0 = &As[(wave * 32) * 32];
    ushort* lA1 = &As[(wave * 32 + 16) * 32];
    ushort* lB0 = &Bs[(wave * 32) * 32];
    ushort* lB1 = &Bs[(wave * 32 + 16) * 32];

    floatx4 acc[4][4];
    #pragma unroll
    for (int i = 0; i < 4; ++i)
        #pragma unroll
        for (int j = 0; j < 4; ++j) {
            acc[i][j][0] = 0.f; acc[i][j][1] = 0.f;
            acc[i][j][2] = 0.f; acc[i][j][3] = 0.f;
        }

    for (int k0 = 0; k0 < KDIM; k0 += 32) {
        __builtin_amdgcn_global_load_lds(AS1C(gA0 + k0), AS3(lA0), 16, 0, 0);
        __builtin_amdgcn_global_load_lds(AS1C(gA1 + k0), AS3(lA1), 16, 0, 0);
        __builtin_amdgcn_global_load_lds(AS1C(gB0 + k0), AS3(lB0), 16, 0, 0);
        __builtin_amdgcn_global_load_lds(AS1C(gB1 + k0), AS3(lB1), 16, 0, 0);
        __syncthreads();

        short8 af[4], bfr[4];
        #pragma unroll
        for (int f = 0; f < 4; ++f) {
            af[f]  = *(const short8*)&As[(wm + f * 16 + l15) * 32 + quad * 8];
            bfr[f] = *(const short8*)&Bs[(wn + f * 16 + l15) * 32 + quad * 8];
        }
        #pragma unroll
        for (int fm = 0; fm < 4; ++fm)
            #pragma unroll
            for (int fn = 0; fn < 4; ++fn)
                acc[fm][fn] = __builtin_amdgcn_mfma_f32_16x16x32_bf16(
                    af[fm], bfr[fn], acc[fm][fn], 0, 0, 0);
        __syncthreads();
    }

    #pragma unroll
    for (int fn = 0; fn < 4; ++fn) {
        const int col = block_n + wn + fn * 16 + l15;
        const float bcol = bias[col];
        #pragma unroll
        for (int fm = 0; fm < 4; ++fm) {
            #pragma unroll
            for (int r = 0; r < 4; ++r) {
                const int row = block_m + wm + fm * 16 + quad * 4 + r;
                Y[(size_t)row * DMODEL + col] = acc[fm][fn][r] + bcol;
            }
        }
    }
}

// ---------------------------------------------------------------------------
// Deformable sampling + online-softmax attention, grouped two-phase.
// Wave = 2 tokens x 8 heads x 4 lanes; each lane owns 8 channels (16B loads).
// Points processed in 3 groups of 3: per group, all 12 K-corner gathers are
// issued before any consumption (12-deep MLP), one softmax update per group,
// then 12 batched V-corner gathers. Packed f32x2 (v_pk_fma_f32) math.
// ---------------------------------------------------------------------------
__global__ __launch_bounds__(256) void deform_attn(
    const ushort* __restrict__ qb,    // (M,256) bf16
    const float* __restrict__ off,    // (M,144) fp32 (tanh*4 applied)
    const ushort* __restrict__ kfb,   // (B*H,N,32) bf16
    const ushort* __restrict__ vfb,
    ushort* __restrict__ attnb)       // (M,256) bf16
{
    const int lane = threadIdx.x & 63;
    const int token = blockIdx.x * 8 + (threadIdx.x >> 6) * 2 + (lane >> 5);
    const int h = (lane >> 2) & 7, lc = lane & 3;
    const int b = token / NTOK, n = token % NTOK;

    const uint4 qu = *(const uint4*)(qb + (size_t)token * DMODEL + h * HDIM + lc * 8);
    f32x2 q2[4]; unpack8v(qu, q2);

    const float* ob = off + (size_t)token * 144 + h * (NPTS * 2);
    const float bx = (float)(n % WSP), by = (float)(n / WSP);
    const ushort* kbase = kfb + (size_t)(b * NHEAD + h) * NTOK * HDIM + lc * 8;
    const ushort* vbase = vfb + (size_t)(b * NHEAD + h) * NTOK * HDIM + lc * 8;

    float m = -INFINITY, s = 0.f;
    f32x2 o2[4];
    #pragma unroll
    for (int i = 0; i < 4; ++i) { o2[i].x = 0.f; o2[i].y = 0.f; }

    #pragma unroll
    for (int g = 0; g < 3; ++g) {
        int   idx[3][4];
        float wt[3][4];
        #pragma unroll
        for (int j = 0; j < 3; ++j) {
            const int p = g * 3 + j;
            const float2 of = *(const float2*)(ob + 2 * p);
            const float sx = bx + of.x, sy = by + of.y;
            const float fx0 = floorf(sx), fy0 = floorf(sy);
            const float wx1 = sx - fx0, wx0 = 1.0f - wx1;
            const float wy1 = sy - fy0, wy0 = 1.0f - wy1;
            const int ix0 = (int)fx0, iy0 = (int)fy0;
            const int ix1 = ix0 + 1, iy1 = iy0 + 1;
            const bool vx0 = (ix0 >= 0) & (ix0 <= WSP - 1);
            const bool vx1 = (ix1 >= 0) & (ix1 <= WSP - 1);
            const bool vy0 = (iy0 >= 0) & (iy0 <= HSP - 1);
            const bool vy1 = (iy1 >= 0) & (iy1 <= HSP - 1);
            const int cx0 = min(max(ix0, 0), WSP - 1);
            const int cx1 = min(max(ix1, 0), WSP - 1);
            const int cy0 = min(max(iy0, 0), HSP - 1);
            const int cy1 = min(max(iy1, 0), HSP - 1);
            wt[j][0] = wx0 * wy0 * (float)(vx0 && vy0);
            wt[j][1] = wx1 * wy0 * (float)(vx1 && vy0);
            wt[j][2] = wx0 * wy1 * (float)(vx0 && vy1);
            wt[j][3] = wx1 * wy1 * (float)(vx1 && vy1);
            idx[j][0] = (cy0 * WSP + cx0) * HDIM;
            idx[j][1] = (cy0 * WSP + cx1) * HDIM;
            idx[j][2] = (cy1 * WSP + cx0) * HDIM;
            idx[j][3] = (cy1 * WSP + cx1) * HDIM;
        }

        // --- K phase: 12 gathers batched, 3 logits ---
        float l[3];
        #pragma unroll
        for (int j = 0; j < 3; ++j) {
            const uint4 k0 = *(const uint4*)(kbase + idx[j][0]);
            const uint4 k1 = *(const uint4*)(kbase + idx[j][1]);
            const uint4 k2 = *(const uint4*)(kbase + idx[j][2]);
            const uint4 k3 = *(const uint4*)(kbase + idx[j][3]);
            float part = wt[j][0] * dot8(k0, q2) + wt[j][1] * dot8(k1, q2)
                       + wt[j][2] * dot8(k2, q2) + wt[j][3] * dot8(k3, q2);
            part += __shfl_xor(part, 1, 64);
            part += __shfl_xor(part, 2, 64);
            l[j] = part * 0.17677669529663687f;   // 32^-0.5
        }

        // --- one online-softmax update per group ---
        const float m1 = fmaxf(fmaxf(fmaxf(l[0], l[1]), l[2]), m);
        const float corr = __expf(m - m1);
        const float e0 = __expf(l[0] - m1);
        const float e1 = __expf(l[1] - m1);
        const float e2 = __expf(l[2] - m1);
        s = s * corr + e0 + e1 + e2;
        m = m1;
        const float e[3] = {e0, e1, e2};

        #pragma unroll
        for (int i = 0; i < 4; ++i) o2[i] *= corr;

        // --- V phase: 12 gathers batched, weighted accumulate ---
        #pragma unroll
        for (int j = 0; j < 3; ++j) {
            #pragma unroll
            for (int c = 0; c < 4; ++c) {
                const uint4 vu = *(const uint4*)(vbase + idx[j][c]);
                f32x2 vv[4]; unpack8v(vu, vv);
                const float ew = e[j] * wt[j][c];
                #pragma unroll
                for (int i = 0; i < 4; ++i) o2[i] += vv[i] * ew;
            }
        }
    }

    const float inv = 1.0f / s;
    uint4 ru;
    ru.x = (uint)f2bf(o2[0].x * inv) | ((uint)f2bf(o2[0].y * inv) << 16);
    ru.y = (uint)f2bf(o2[1].x * inv) | ((uint)f2bf(o2[1].y * inv) << 16);
    ru.z = (uint)f2bf(o2[2].x * inv) | ((uint)f2bf(o2[2].y * inv) << 16);
    ru.w = (uint)f2bf(o2[3].x * inv) | ((uint)f2bf(o2[3].y * inv) << 16);
    *(uint4*)(attnb + (size_t)token * DMODEL + h * HDIM + lc * 8) = ru;
}

// ---------------------------------------------------------------------------
extern "C" void kernel_launch(void* const* d_in, const int* in_sizes, int n_in,
                              void* d_out, int out_size, void* d_ws, size_t ws_size,
                              hipStream_t stream) {
    const float* x    = (const float*)d_in[0];
    const float* Wq   = (const float*)d_in[1];
    const float* bq   = (const float*)d_in[2];
    const float* Woff = (const float*)d_in[3];
    const float* boff = (const float*)d_in[4];
    const float* Wkv  = (const float*)d_in[5];
    const float* bkv  = (const float*)d_in[6];
    const float* Wout = (const float*)d_in[7];
    const float* bout = (const float*)d_in[8];

    // workspace layout (~68 MB)
    ushort* xb    = (ushort*)d_ws;                         // 6,553,600 us (aliased by attnb)
    ushort* qb    = xb + (size_t)MTOT * DMODEL;            // 6,553,600 us
    float*  off   = (float*)(qb + (size_t)MTOT * DMODEL);  // 3,686,400 f32
    ushort* kfb   = (ushort*)(off + (size_t)MTOT * 144);   // 6,553,600 us
    ushort* vfb   = kfb + (size_t)MTOT * DMODEL;           // 6,553,600 us
    ushort* wf    = vfb + (size_t)MTOT * DMODEL;           // 262,144 us (1024x256)
    ushort* woutb = wf + 262144;                           // 65,536 us
    ushort* attnb = xb;   // xb dead after gemm_fused

    cast_all<<<dim3(6720), dim3(256), 0, stream>>>(x, Wq, Woff, Wkv, Wout,
                                                   xb, wf, woutb);

    gemm_fused<<<dim3(8, 200), dim3(256), 0, stream>>>(xb, wf, bq, boff, bkv,
                                                       qb, off, kfb, vfb);

    deform_attn<<<dim3(3200), dim3(256), 0, stream>>>(qb, off, kfb, vfb, attnb);

    gemm_out<<<dim3(2, 200), dim3(256), 0, stream>>>(attnb, woutb, bout,
                                                     (float*)d_out);
}